// Round 12
// baseline (450.089 us; speedup 1.0000x reference)
//
#include <hip/hip_runtime.h>
#include <hip/hip_bf16.h>

#define NA 4096
#define DD 256
#define HH 4
#define CC 64
#define LL 2
#define TOPK 5
#define NSLICE 4

typedef __hip_bfloat16 bf16;
typedef __attribute__((ext_vector_type(8))) short bf16x8;
typedef __attribute__((ext_vector_type(4))) float f32x4;

__device__ __forceinline__ float b2f(bf16 v) { return __bfloat162float(v); }
__device__ __forceinline__ float u2f(unsigned int u) { union { unsigned int i; float f; } x; x.i = u; return x.f; }
__device__ __forceinline__ unsigned short f2bf(float f) {
  bf16 b = __float2bfloat16(f);
  return *reinterpret_cast<unsigned short*>(&b);
}
__device__ __forceinline__ float ldx(const void* p, size_t i, int bfm) {
  return bfm ? b2f(((const bf16*)p)[i]) : ((const float*)p)[i];
}
// strict ordering used by jax.lax.top_k: larger value first, ties -> smaller index
__device__ __forceinline__ bool kbetter(float v, int c, float v2, int c2) {
  return (v > v2) || (v == v2 && c < c2);
}
// monotone float->u32 key with col tie-break in low 12 bits (smaller col = larger key)
__device__ __forceinline__ unsigned int fkey(float f, int col) {
  unsigned int b = __float_as_uint(f);
  unsigned int u = ((int)b < 0) ? ~b : (b | 0x80000000u);
  return (u & 0xFFFFF000u) | (4095u - (unsigned int)col);
}

// ---------------- dtype detect: bf16 vs fp32 ----------------
__global__ __launch_bounds__(256) void k_detect(const void* probe, int* flag) {
  __shared__ int cnt;
  if (threadIdx.x == 0) cnt = 0;
  __syncthreads();
  const unsigned short* u = (const unsigned short*)probe;
  int bad = 0;
  for (int i = threadIdx.x; i < 2048; i += 256) {
    float v = u2f(((unsigned int)u[i]) << 16);
    if (!(fabsf(v) <= 1e10f)) bad++;
  }
  atomicAdd(&cnt, bad);
  __syncthreads();
  if (threadIdx.x == 0) flag[0] = (cnt < 64) ? 1 : 0;
}

// ---------------- weight transpose: Wt[n][k] = W[k][n], bf16 out, zero-pad n>=N ----------------
struct WtD { const void* src; long srcOff; int N; int K; long dstOff; };
struct WtArr { WtD d[10]; };

__global__ __launch_bounds__(256) void k_wT(WtArr wa, const int* __restrict__ flag, bf16* __restrict__ dst) {
  __shared__ unsigned short T[32][34];
  WtD de = wa.d[blockIdx.y];
  int bfm = flag[0];
  int Npad = ((de.N + 63) / 64) * 64;
  int tilesN = Npad >> 5, tilesK = de.K >> 5;
  int tile = blockIdx.x;
  if (tile >= tilesN * tilesK) return;
  int tn = tile % tilesN, tk = tile / tilesN;
  int t = threadIdx.x;
  {
    int kl = t >> 3, n4 = (t & 7) * 4;
    int kg = tk*32 + kl;
    #pragma unroll
    for (int j = 0; j < 4; j++) {
      int n = tn*32 + n4 + j;
      float v = (n < de.N) ? ldx(de.src, de.srcOff + (size_t)kg * de.N + n, bfm) : 0.0f;
      T[kl][n4 + j] = f2bf(v);
    }
  }
  __syncthreads();
  {
    int nl = t >> 3, k4 = (t & 7) * 4;
    size_t base = de.dstOff + (size_t)(tn*32 + nl) * de.K + tk*32 + k4;
    #pragma unroll
    for (int j = 0; j < 4; j++)
      ((unsigned short*)dst)[base + j] = T[k4 + j][nl];
  }
}

// ---------------- prep: statesF, enhanced, normalized rows (fp32 + bf16) ----------------
__global__ __launch_bounds__(256) void k_prep(
    const void* __restrict__ st, const void* __restrict__ em, const void* __restrict__ ro,
    const int* __restrict__ flag,
    float* __restrict__ statesF, float* __restrict__ enh, float* __restrict__ nsm,
    bf16* __restrict__ nsmh)
{
  int i = blockIdx.x, d = threadIdx.x;
  int bfm = flag[0];
  __shared__ float red[256];
  float s = ldx(st, (size_t)i*DD + d, bfm);
  statesF[i*DD + d] = s;
  float e = s + ldx(em, (size_t)i*DD + d, bfm) + ldx(ro, (size_t)i*64 + (d & 63), bfm);
  enh[i*DD + d] = e;
  red[d] = e * e;
  __syncthreads();
  for (int k = 128; k > 0; k >>= 1) { if (d < k) red[d] += red[d + k]; __syncthreads(); }
  float inv = 1.0f / fmaxf(sqrtf(red[0]), 1e-12f);
  float nv = e * inv;
  nsm[i*DD + d] = nv;
  nsmh[i*DD + d] = __float2bfloat16(nv);
}

// ---------------- MFMA sim + branchless top-8 (u32 keys, max/min networks) ----------------
__global__ __launch_bounds__(256) void k_sim2(
    const bf16* __restrict__ nsmh, int* __restrict__ candI)
{
  int tid = threadIdx.x;
  int lane = tid & 63;
  int w = tid >> 6;
  int lr = lane & 15;
  int lg = lane >> 4;
  int chunk = blockIdx.x;
  int rb = blockIdx.y * 64;
  int cb = chunk * 256;
  const unsigned short* nsu = (const unsigned short*)nsmh;

  bf16x8 af[8];
  {
    const unsigned short* ap = nsu + (size_t)(rb + w*16 + lr)*DD + lg*8;
    #pragma unroll
    for (int kb = 0; kb < 8; kb++) af[kb] = *(const bf16x8*)(ap + kb*32);
  }

  unsigned int L0[8] = {0,0,0,0,0,0,0,0};
  unsigned int L1[8] = {0,0,0,0,0,0,0,0};
  unsigned int L2[8] = {0,0,0,0,0,0,0,0};
  unsigned int L3[8] = {0,0,0,0,0,0,0,0};

  #pragma unroll
  for (int ct = 0; ct < 16; ct++) {
    int c0 = cb + ct * 16;
    const unsigned short* bp = nsu + (size_t)(c0 + lr)*DD + lg*8;
    f32x4 z = (f32x4){0.f, 0.f, 0.f, 0.f};
    #pragma unroll
    for (int kb = 0; kb < 8; kb++) {
      bf16x8 bfr = *(const bf16x8*)(bp + kb*32);
      z = __builtin_amdgcn_mfma_f32_16x16x32_bf16(af[kb], bfr, z, 0, 0, 0);
    }
    int c = c0 + lr;
    unsigned int s0 = fkey(z[0], c), s1 = fkey(z[1], c), s2 = fkey(z[2], c), s3 = fkey(z[3], c);
    #pragma unroll
    for (int i = 0; i < 8; i++) {
      unsigned int h0 = max(L0[i], s0); s0 = min(L0[i], s0); L0[i] = h0;
      unsigned int h1 = max(L1[i], s1); s1 = min(L1[i], s1); L1[i] = h1;
      unsigned int h2 = max(L2[i], s2); s2 = min(L2[i], s2); L2[i] = h2;
      unsigned int h3 = max(L3[i], s3); s3 = min(L3[i], s3); L3[i] = h3;
    }
  }

  unsigned int* Ls[4] = { L0, L1, L2, L3 };
  #pragma unroll
  for (int r = 0; r < 4; r++) {
    unsigned int* a = Ls[r];
    #pragma unroll
    for (int st = 0; st < 4; st++) {
      const int msk = 1 << st;
      unsigned int t[8];
      #pragma unroll
      for (int i = 0; i < 8; i++) {
        unsigned int ob = __shfl_xor((int)a[7 - i], msk);
        t[i] = max(a[i], ob);
      }
      #pragma unroll
      for (int i = 0; i < 4; i++) {
        unsigned int hi = max(t[i], t[i+4]); unsigned int lo = min(t[i], t[i+4]);
        t[i] = hi; t[i+4] = lo;
      }
      #pragma unroll
      for (int g = 0; g < 8; g += 4) {
        #pragma unroll
        for (int i = 0; i < 2; i++) {
          unsigned int hi = max(t[g+i], t[g+i+2]); unsigned int lo = min(t[g+i], t[g+i+2]);
          t[g+i] = hi; t[g+i+2] = lo;
        }
      }
      #pragma unroll
      for (int g = 0; g < 8; g += 2) {
        unsigned int hi = max(t[g], t[g+1]); unsigned int lo = min(t[g], t[g+1]);
        t[g] = hi; t[g+1] = lo;
      }
      #pragma unroll
      for (int i = 0; i < 8; i++) a[i] = t[i];
    }
  }
  if (lr == 0) {
    #pragma unroll
    for (int r = 0; r < 4; r++) {
      int row = rb + w*16 + lg*4 + r;
      #pragma unroll
      for (int k = 0; k < 8; k++)
        candI[(size_t)row*128 + chunk*8 + k] = 4095 - (int)(Ls[r][k] & 0xFFFu);
    }
  }
}

// ---------------- exact fp32 rescore of 128 candidates -> top-5 + adjacency bits ----------------
// one block per row; 16 lane-groups x 8 candidates; wave-0 exact top-5 argmax
__global__ __launch_bounds__(256) void k_topk2(
    const float* __restrict__ nsb, const int* __restrict__ candI,
    unsigned long long* __restrict__ maskbits)
{
  __shared__ float sV[128];
  __shared__ int   sI[128];
  int row = blockIdx.x;
  int tid = threadIdx.x;
  int g = tid >> 4;        // group 0..15
  int l = tid & 15;        // lane-in-group
  const float* ap = &nsb[(size_t)row*DD];
  float4 a0 = *(const float4*)(ap + 0*64 + l*4);
  float4 a1 = *(const float4*)(ap + 1*64 + l*4);
  float4 a2 = *(const float4*)(ap + 2*64 + l*4);
  float4 a3 = *(const float4*)(ap + 3*64 + l*4);
  #pragma unroll
  for (int it = 0; it < 8; it++) {
    int c = g*8 + it;
    int ci = candI[(size_t)row*128 + c];
    const float* bp = &nsb[(size_t)ci*DD];
    float4 b0 = *(const float4*)(bp + 0*64 + l*4);
    float4 b1 = *(const float4*)(bp + 1*64 + l*4);
    float4 b2 = *(const float4*)(bp + 2*64 + l*4);
    float4 b3 = *(const float4*)(bp + 3*64 + l*4);
    float p = a0.x*b0.x + a0.y*b0.y + a0.z*b0.z + a0.w*b0.w
            + a1.x*b1.x + a1.y*b1.y + a1.z*b1.z + a1.w*b1.w
            + a2.x*b2.x + a2.y*b2.y + a2.z*b2.z + a2.w*b2.w
            + a3.x*b3.x + a3.y*b3.y + a3.z*b3.z + a3.w*b3.w;
    p += __shfl_xor(p, 1); p += __shfl_xor(p, 2);
    p += __shfl_xor(p, 4); p += __shfl_xor(p, 8);
    if (l == 0) { sV[c] = p; sI[c] = ci; }
  }
  __syncthreads();
  if (tid < 64) {
    float v0 = sV[tid], v1 = sV[64 + tid];
    int   i0 = sI[tid], i1 = sI[64 + tid];
    int sel[5];
    #pragma unroll
    for (int k = 0; k < 5; k++) {
      float bv; int bi;
      if (kbetter(v0, i0, v1, i1)) { bv = v0; bi = i0; } else { bv = v1; bi = i1; }
      #pragma unroll
      for (int off = 1; off < 64; off <<= 1) {
        float ov = __shfl_xor(bv, off); int oi = __shfl_xor(bi, off);
        if (kbetter(ov, oi, bv, bi)) { bv = ov; bi = oi; }
      }
      sel[k] = bi;
      if (i0 == bi) { v0 = -1e30f; i0 = 0x7fffffff; }
      if (i1 == bi) { v1 = -1e30f; i1 = 0x7fffffff; }
    }
    if (tid == 0) {
      atomicOr(&maskbits[(size_t)row*64 + (row >> 6)], 1ull << (row & 63));
      #pragma unroll
      for (int k = 0; k < 5; k++) {
        int j = sel[k];
        atomicOr(&maskbits[(size_t)row*64 + (j >> 6)], 1ull << (j & 63));
        atomicOr(&maskbits[(size_t)j*64 + (row >> 6)], 1ull << (row & 63));
      }
    }
  }
}

// ---------------- MFMA GEMM: C[M,N] = act(A[M,K] @ Wt^T + bias) (+resid / accF) ----------------
// 16-row M-tiles: grid (Npad/64, NA/16), 4 waves each own a 16x16 output tile.
template<int KB>
__global__ __launch_bounds__(256) void k_mgemm(
    const float* __restrict__ A, const bf16* __restrict__ Bt, int ldB,
    const void* __restrict__ bias, const float* __restrict__ resid,
    const int* __restrict__ flag,
    float* __restrict__ Cf, void* __restrict__ Cb,
    int N, int act, int accF, int smode)
{
  int bfm = flag[0];
  int tid = threadIdx.x;
  int lane = tid & 63, w = tid >> 6;
  int lr = lane & 15, lg = lane >> 4;
  int n0 = blockIdx.x * 64 + w * 16;
  int m0 = blockIdx.y * 16;
  const int K = KB * 32;
  int arow = m0 + lr;

  bf16x8 af[KB];
  #pragma unroll
  for (int kb = 0; kb < KB; kb++) {
    const float* ap = A + (size_t)arow*K + kb*32 + lg*8;
    float4 v0 = *(const float4*)ap;
    float4 v1 = *(const float4*)(ap + 4);
    bf16x8 tt;
    tt[0] = (short)f2bf(v0.x); tt[1] = (short)f2bf(v0.y);
    tt[2] = (short)f2bf(v0.z); tt[3] = (short)f2bf(v0.w);
    tt[4] = (short)f2bf(v1.x); tt[5] = (short)f2bf(v1.y);
    tt[6] = (short)f2bf(v1.z); tt[7] = (short)f2bf(v1.w);
    af[kb] = tt;
  }

  f32x4 acc = (f32x4){0.f,0.f,0.f,0.f};
  const unsigned short* bu = (const unsigned short*)Bt;
  const unsigned short* bp = bu + (size_t)(n0 + lr)*ldB + lg*8;
  #pragma unroll
  for (int kb = 0; kb < KB; kb++) {
    bf16x8 bfr = *(const bf16x8*)(bp + kb*32);
    acc = __builtin_amdgcn_mfma_f32_16x16x32_bf16(af[kb], bfr, acc, 0, 0, 0);
  }

  int col = n0 + lr;
  if (col < N) {
    #pragma unroll
    for (int r = 0; r < 4; r++) {
      int orow = m0 + lg*4 + r;
      size_t idx = (size_t)orow*N + col;
      float v = acc[r];
      if (accF) v += Cf[idx];
      if (bias) v += ldx(bias, col, bfm);
      if (act == 1) v = fmaxf(v, 0.0f);
      if (resid) v += resid[idx];
      if (smode == 0) Cf[idx] = v;
      else if (smode == 1) ((bf16*)Cb)[idx] = __float2bfloat16(v);
      else {
        if (bfm) ((bf16*)Cb)[idx] = __float2bfloat16(v);
        else ((float*)Cb)[idx] = v;
      }
    }
  }
}

// ---------------- a_s, a_d ----------------
__global__ __launch_bounds__(256) void k_asd(
    const float* __restrict__ xs, const void* __restrict__ asrc, const void* __restrict__ adst,
    long loff, const int* __restrict__ flag,
    float* __restrict__ aS, float* __restrict__ aD)
{
  int i = blockIdx.x, t = threadIdx.x;
  int bfm = flag[0];
  __shared__ float rs[256], rd[256];
  float xv = xs[(size_t)i*DD + t];
  rs[t] = xv * ldx(asrc, loff + t, bfm);
  rd[t] = xv * ldx(adst, loff + t, bfm);
  __syncthreads();
  for (int k = 32; k > 0; k >>= 1) {
    if ((t & 63) < k) { rs[t] += rs[t + k]; rd[t] += rd[t + k]; }
    __syncthreads();
  }
  if ((t & 63) == 0) { int h = t >> 6; aS[i*HH + h] = rs[t]; aD[i*HH + h] = rd[t]; }
}

// ---------------- GAT aggregation + bias + LN + residual ----------------
__global__ __launch_bounds__(256) void k_gatagg(
    const float* __restrict__ xs, const float* __restrict__ aS, const float* __restrict__ aD,
    const unsigned long long* __restrict__ maskbits,
    const void* __restrict__ gbias, const void* __restrict__ lng, const void* __restrict__ lnb,
    long loff, const int* __restrict__ flag,
    const float* __restrict__ xold, float* __restrict__ xnew)
{
  __shared__ int nbr[NA];
  __shared__ float alph[NA];
  __shared__ float red[256];
  __shared__ float outv[DD];
  __shared__ int offs[64];
  __shared__ int degS;
  int j = blockIdx.x, t = threadIdx.x;
  int bfm = flag[0];
  unsigned long long bits = 0;
  if (t < 64) { bits = maskbits[(size_t)j*64 + t]; offs[t] = __popcll(bits); }
  __syncthreads();
  if (t == 0) { int run = 0; for (int w = 0; w < 64; w++) { int c = offs[w]; offs[w] = run; run += c; } degS = run; }
  __syncthreads();
  if (t < 64) {
    int base = offs[t];
    unsigned long long b = bits;
    while (b) { int p = __builtin_ctzll(b); nbr[base++] = t*64 + p; b &= b - 1; }
  }
  __syncthreads();
  int deg = degS;
  for (int h = 0; h < HH; h++) {
    float adjv = aD[j*HH + h];
    float lm = -1e30f;
    for (int n = t; n < deg; n += 256) {
      float lg = aS[nbr[n]*HH + h] + adjv;
      lg = (lg >= 0.f) ? lg : 0.2f*lg;
      alph[n] = lg;
      lm = fmaxf(lm, lg);
    }
    red[t] = lm; __syncthreads();
    for (int k = 128; k > 0; k >>= 1) { if (t < k) red[t] = fmaxf(red[t], red[t + k]); __syncthreads(); }
    float Mx = red[0];
    __syncthreads();
    float ls = 0.f;
    for (int n = t; n < deg; n += 256) { float w = __expf(alph[n] - Mx); alph[n] = w; ls += w; }
    red[t] = ls; __syncthreads();
    for (int k = 128; k > 0; k >>= 1) { if (t < k) red[t] += red[t + k]; __syncthreads(); }
    float Z = red[0];
    __syncthreads();
    int c = t & 63, q = t >> 6;
    float a2 = 0.f;
    for (int n = q; n < deg; n += 4) a2 += alph[n] * xs[(size_t)nbr[n]*DD + h*CC + c];
    red[t] = a2; __syncthreads();
    if (q == 0) outv[h*CC + c] = (red[c] + red[c+64] + red[c+128] + red[c+192]) / Z;
    __syncthreads();
  }
  float v = outv[t] + ldx(gbias, loff + t, bfm);
  red[t] = v; __syncthreads();
  for (int k = 128; k > 0; k >>= 1) { if (t < k) red[t] += red[t + k]; __syncthreads(); }
  float mu = red[0] * (1.0f/DD);
  __syncthreads();
  float dv = v - mu;
  red[t] = dv*dv; __syncthreads();
  for (int k = 128; k > 0; k >>= 1) { if (t < k) red[t] += red[t + k]; __syncthreads(); }
  float var = red[0] * (1.0f/DD);
  float xn = ldx(lng, loff + t, bfm) * dv * rsqrtf(var + 1e-5f) + ldx(lnb, loff + t, bfm) + xold[(size_t)j*DD + t];
  xnew[(size_t)j*DD + t] = xn;
}

// ---------------- KV-split MFMA flash-MHA with coalesced LDS staging ----------------
__global__ __launch_bounds__(256) void k_mha2s(
    const bf16* __restrict__ qkvb,
    bf16* __restrict__ pacc, float* __restrict__ pm, float* __restrict__ pl)
{
  __shared__ unsigned short Ks[64][72];
  __shared__ unsigned short Vts[64][72];
  __shared__ unsigned short Ps[4][16][72];
  int tid = threadIdx.x;
  int lane = tid & 63;
  int w = tid >> 6;
  int h = blockIdx.y;
  int q0 = blockIdx.x * 64;
  int sl = blockIdx.z;
  int lr = lane & 15;
  int lg = lane >> 4;

  const unsigned short* qkvu = (const unsigned short*)qkvb;

  bf16x8 qf0, qf1;
  {
    const unsigned short* qp = qkvu + (size_t)(q0 + w*16 + lr)*768 + h*64;
    qf0 = *(const bf16x8*)(qp + lg*8);
    qf1 = *(const bf16x8*)(qp + 32 + lg*8);
  }

  int sr = tid & 63;
  int sc = (tid >> 6) * 16;
  const unsigned short* kbase = qkvu + 256 + h*64;
  const unsigned short* vbase = qkvu + 512 + h*64;

  f32x4 oacc[4];
  #pragma unroll
  for (int c = 0; c < 4; c++) oacc[c] = (f32x4){0.f,0.f,0.f,0.f};
  float mrun[4], lrun[4];
  #pragma unroll
  for (int r = 0; r < 4; r++) { mrun[r] = -1e30f; lrun[r] = 0.f; }

  const int j0base = sl * (NA / NSLICE);
  bf16x8 kpa, kpb, vpa, vpb;
  {
    const unsigned short* kp = kbase + (size_t)(j0base + sr)*768 + sc;
    kpa = *(const bf16x8*)kp; kpb = *(const bf16x8*)(kp + 8);
    const unsigned short* vp = vbase + (size_t)(j0base + sr)*768 + sc;
    vpa = *(const bf16x8*)vp; vpb = *(const bf16x8*)(vp + 8);
  }

  for (int tile = 0; tile < (NA/NSLICE)/64; tile++) {
    int j0 = j0base + tile * 64;
    __syncthreads();
    *(bf16x8*)&Ks[sr][sc] = kpa;
    *(bf16x8*)&Ks[sr][sc+8] = kpb;
    {
      #pragma unroll
      for (int q = 0; q < 8; q++) Vts[sc + q][sr] = (unsigned short)vpa[q];
      #pragma unroll
      for (int q = 0; q < 8; q++) Vts[sc + 8 + q][sr] = (unsigned short)vpb[q];
    }
    __syncthreads();
    if (tile + 1 < (NA/NSLICE)/64) {
      const unsigned short* kp = kbase + (size_t)(j0 + 64 + sr)*768 + sc;
      kpa = *(const bf16x8*)kp; kpb = *(const bf16x8*)(kp + 8);
      const unsigned short* vp = vbase + (size_t)(j0 + 64 + sr)*768 + sc;
      vpa = *(const bf16x8*)vp; vpb = *(const bf16x8*)(vp + 8);
    }
    f32x4 sacc[4];
    #pragma unroll
    for (int ct = 0; ct < 4; ct++) {
      bf16x8 kf0 = *(bf16x8*)&Ks[ct*16 + lr][lg*8];
      bf16x8 kf1 = *(bf16x8*)&Ks[ct*16 + lr][32 + lg*8];
      f32x4 z = (f32x4){0.f,0.f,0.f,0.f};
      z = __builtin_amdgcn_mfma_f32_16x16x32_bf16(qf0, kf0, z, 0, 0, 0);
      z = __builtin_amdgcn_mfma_f32_16x16x32_bf16(qf1, kf1, z, 0, 0, 0);
      sacc[ct] = z;
    }
    #pragma unroll
    for (int r = 0; r < 4; r++) {
      float s0 = sacc[0][r]*0.125f, s1 = sacc[1][r]*0.125f;
      float s2 = sacc[2][r]*0.125f, s3 = sacc[3][r]*0.125f;
      float rm = fmaxf(fmaxf(s0, s1), fmaxf(s2, s3));
      rm = fmaxf(rm, __shfl_xor(rm, 1));
      rm = fmaxf(rm, __shfl_xor(rm, 2));
      rm = fmaxf(rm, __shfl_xor(rm, 4));
      rm = fmaxf(rm, __shfl_xor(rm, 8));
      float mn = fmaxf(mrun[r], rm);
      float corr = __expf(mrun[r] - mn);
      float p0 = __expf(s0 - mn), p1 = __expf(s1 - mn);
      float p2 = __expf(s2 - mn), p3 = __expf(s3 - mn);
      float ps = p0 + p1 + p2 + p3;
      ps += __shfl_xor(ps, 1); ps += __shfl_xor(ps, 2);
      ps += __shfl_xor(ps, 4); ps += __shfl_xor(ps, 8);
      mrun[r] = mn;
      lrun[r] = lrun[r]*corr + ps;
      #pragma unroll
      for (int c = 0; c < 4; c++) oacc[c][r] *= corr;
      int prow = lg*4 + r;
      Ps[w][prow][ 0 + lr] = f2bf(p0);
      Ps[w][prow][16 + lr] = f2bf(p1);
      Ps[w][prow][32 + lr] = f2bf(p2);
      Ps[w][prow][48 + lr] = f2bf(p3);
    }
    {
      bf16x8 pa0 = *(bf16x8*)&Ps[w][lr][lg*8];
      bf16x8 pa1 = *(bf16x8*)&Ps[w][lr][32 + lg*8];
      #pragma unroll
      for (int c = 0; c < 4; c++) {
        bf16x8 vf0 = *(bf16x8*)&Vts[c*16 + lr][lg*8];
        bf16x8 vf1 = *(bf16x8*)&Vts[c*16 + lr][32 + lg*8];
        oacc[c] = __builtin_amdgcn_mfma_f32_16x16x32_bf16(pa0, vf0, oacc[c], 0, 0, 0);
        oacc[c] = __builtin_amdgcn_mfma_f32_16x16x32_bf16(pa1, vf1, oacc[c], 0, 0, 0);
      }
    }
  }
  #pragma unroll
  for (int r = 0; r < 4; r++) {
    int row = q0 + w*16 + lg*4 + r;
    #pragma unroll
    for (int c = 0; c < 4; c++)
      pacc[((size_t)sl*NA + row)*DD + h*CC + c*16 + lr] = __float2bfloat16(oacc[c][r]);
  }
  if (lr == 0) {
    #pragma unroll
    for (int r = 0; r < 4; r++) {
      int row = q0 + w*16 + lg*4 + r;
      pm[((size_t)sl*HH + h)*NA + row] = mrun[r];
      pl[((size_t)sl*HH + h)*NA + row] = lrun[r];
    }
  }
}

// ---------------- combine KV-split partials ----------------
__global__ __launch_bounds__(256) void k_mhacomb(
    const bf16* __restrict__ pacc, const float* __restrict__ pm, const float* __restrict__ pl,
    float* __restrict__ ctx)
{
  int row = blockIdx.x, col = threadIdx.x;
  int h = col >> 6;
  float ms[NSLICE];
  float M = -1e30f;
  #pragma unroll
  for (int s = 0; s < NSLICE; s++) { ms[s] = pm[((size_t)s*HH + h)*NA + row]; M = fmaxf(M, ms[s]); }
  float O = 0.f, L = 0.f;
  #pragma unroll
  for (int s = 0; s < NSLICE; s++) {
    float e = __expf(ms[s] - M);
    O += e * b2f(pacc[((size_t)s*NA + row)*DD + col]);
    L += e * pl[((size_t)s*HH + h)*NA + row];
  }
  ctx[(size_t)row*DD + col] = O / L;
}

// ---------------- gate ----------------
__global__ __launch_bounds__(256) void k_gate(
    const float* __restrict__ g1, const void* __restrict__ w2, const void* __restrict__ b2v,
    const int* __restrict__ flag,
    const float* __restrict__ agg, float* __restrict__ ag2)
{
  int i = blockIdx.x, t = threadIdx.x;
  int bfm = flag[0];
  __shared__ float red[256];
  red[t] = g1[(size_t)i*DD + t] * ldx(w2, t, bfm);
  __syncthreads();
  for (int k = 128; k > 0; k >>= 1) { if (t < k) red[t] += red[t + k]; __syncthreads(); }
  float sr = red[0] + ldx(b2v, 0, bfm);
  float s = 1.0f / (1.0f + __expf(-sr));
  ag2[(size_t)i*DD + t] = agg[(size_t)i*DD + t] * s;
}

extern "C" void kernel_launch(void* const* d_in, const int* in_sizes, int n_in,
                              void* d_out, int out_size, void* d_ws, size_t ws_size,
                              hipStream_t stream) {
  (void)in_sizes; (void)n_in; (void)out_size; (void)ws_size;
  const void* agent_states = d_in[0];
  const void* agent_emb    = d_in[1];
  const void* role_emb     = d_in[2];
  const void* gat_W        = d_in[3];
  const void* gat_att_src  = d_in[4];
  const void* gat_att_dst  = d_in[5];
  const void* gat_bias     = d_in[6];
  const void* ln_gamma     = d_in[7];
  const void* ln_beta      = d_in[8];
  const void* enc_W1 = d_in[9];
  const void* enc_b1 = d_in[10];
  const void* enc_W2 = d_in[11];
  const void* enc_b2 = d_in[12];
  const void* dec_W1 = d_in[13];
  const void* dec_b1 = d_in[14];
  const void* dec_W2 = d_in[15];
  const void* dec_b2 = d_in[16];
  const void* mha_in_w  = d_in[17];
  const void* mha_in_b  = d_in[18];
  const void* mha_out_w = d_in[19];
  const void* mha_out_b = d_in[20];
  const void* proj_W = d_in[21];
  const void* proj_b = d_in[22];
  const void* gate_W1 = d_in[23];
  const void* gate_b1 = d_in[24];
  const void* gate_W2 = d_in[25];
  const void* gate_b2 = d_in[26];

  char* base = (char*)d_ws;
  size_t off = 0;
  auto alloc = [&](size_t nbytes) -> char* {
    char* p = base + off; off += (nbytes + 255) & ~(size_t)255; return p;
  };
  int* flag = (int*)alloc(256);
  float* statesF = (float*)alloc((size_t)NA*DD*4);
  float* enh     = (float*)alloc((size_t)NA*DD*4);
  float* nsb     = (float*)alloc((size_t)NA*DD*4);
  bf16*  nsbh    = (bf16*)alloc((size_t)NA*DD*2);
  unsigned long long* maskbits = (unsigned long long*)alloc((size_t)NA*64*8);
  float* xs  = (float*)alloc((size_t)NA*DD*4);
  float* xB  = (float*)alloc((size_t)NA*DD*4);
  bf16*  qkvb = (bf16*)alloc((size_t)NA*3*DD*2);
  float* dec = (float*)alloc((size_t)NA*DD*4);
  float* agg = (float*)alloc((size_t)NA*DD*4);
  int*   candI = (int*)alloc((size_t)NA*128*4);
  bf16*  wt    = (bf16*)alloc((size_t)647168*2);
  bf16*  pacc  = (bf16*)alloc((size_t)NSLICE*NA*DD*2);
  float* pm    = (float*)alloc((size_t)NSLICE*HH*NA*4);
  float* pl    = (float*)alloc((size_t)NSLICE*HH*NA*4);
  float* xC  = enh;
  float* aS  = nsb;               // nsb free after k_topk2
  float* aD  = nsb + NA*HH;
  float* h1  = nsb + 2*NA*HH;
  float* msg = h1 + (size_t)NA*64;
  float* dh  = msg + (size_t)NA*32;
  float* ctx = dec;
  float* g1  = xs;
  float* ag2 = xB;

  // transposed-weight element offsets (each block is [Npad][K] bf16)
  const long o_gat0 = 0,      o_gat1 = 65536,  o_enc1 = 131072, o_enc2 = 147456;
  const long o_dec1 = 151552, o_dec2 = 155648, o_qkv  = 188416, o_out  = 385024;
  const long o_gate = 450560, o_proj = 581632;

  WtArr wa;
  wa.d[0] = { gat_W,     0,      256, 256, o_gat0 };
  wa.d[1] = { gat_W,     65536,  256, 256, o_gat1 };
  wa.d[2] = { enc_W1,    0,       64, 256, o_enc1 };
  wa.d[3] = { enc_W2,    0,       32,  64, o_enc2 };
  wa.d[4] = { dec_W1,    0,      128,  32, o_dec1 };
  wa.d[5] = { dec_W2,    0,      256, 128, o_dec2 };
  wa.d[6] = { mha_in_w,  0,      768, 256, o_qkv  };
  wa.d[7] = { mha_out_w, 0,      256, 256, o_out  };
  wa.d[8] = { gate_W1,   0,      256, 512, o_gate };
  wa.d[9] = { proj_W,    0,      256, 256, o_proj };

  auto mgemm = [&](const float* A, const bf16* Bt, int ldB, const void* bias,
                   const float* resid, float* Cf, void* Cb,
                   int N, int Npad, int K, int act, int accF, int smode) {
    dim3 g(Npad/64, NA/16);
    switch (K/32) {
      case 1: hipLaunchKernelGGL(k_mgemm<1>, g, dim3(256), 0, stream, A, Bt, ldB, bias, resid, flag, Cf, Cb, N, act, accF, smode); break;
      case 2: hipLaunchKernelGGL(k_mgemm<2>, g, dim3(256), 0, stream, A, Bt, ldB, bias, resid, flag, Cf, Cb, N, act, accF, smode); break;
      case 4: hipLaunchKernelGGL(k_mgemm<4>, g, dim3(256), 0, stream, A, Bt, ldB, bias, resid, flag, Cf, Cb, N, act, accF, smode); break;
      default: hipLaunchKernelGGL(k_mgemm<8>, g, dim3(256), 0, stream, A, Bt, ldB, bias, resid, flag, Cf, Cb, N, act, accF, smode); break;
    }
  };

  hipMemsetAsync(maskbits, 0, (size_t)NA*64*8, stream);
  hipLaunchKernelGGL(k_detect, dim3(1), dim3(256), 0, stream, agent_states, flag);
  hipLaunchKernelGGL(k_wT, dim3(192, 10), dim3(256), 0, stream, wa, flag, wt);
  hipLaunchKernelGGL(k_prep, dim3(NA), dim3(256), 0, stream,
                     agent_states, agent_emb, role_emb, flag, statesF, enh, nsb, nsbh);
  hipLaunchKernelGGL(k_sim2, dim3(16, NA/64), dim3(256), 0, stream, nsbh, candI);
  hipLaunchKernelGGL(k_topk2, dim3(NA), dim3(256), 0, stream, nsb, candI, maskbits);

  const float* xin = enh;
  float* xout = xB;
  for (int l = 0; l < LL; l++) {
    mgemm(xin, wt + (l ? o_gat1 : o_gat0), 256, nullptr, nullptr, xs, nullptr, 256, 256, 256, 0, 0, 0);
    hipLaunchKernelGGL(k_asd, dim3(NA), dim3(256), 0, stream,
                       xs, gat_att_src, gat_att_dst, (long)l*DD, flag, aS, aD);
    hipLaunchKernelGGL(k_gatagg, dim3(NA), dim3(256), 0, stream,
                       xs, aS, aD, maskbits, gat_bias, ln_gamma, ln_beta, (long)l*DD, flag, xin, xout);
    xin = xout; xout = xC;
  }
  mgemm(xin, wt + o_enc1, 256, enc_b1, nullptr, h1, nullptr, 64, 64, 256, 1, 0, 0);
  mgemm(h1, wt + o_enc2, 64, enc_b2, nullptr, msg, nullptr, 32, 64, 64, 0, 0, 0);
  mgemm(msg, wt + o_dec1, 32, dec_b1, nullptr, dh, nullptr, 128, 128, 32, 1, 0, 0);
  mgemm(dh, wt + o_dec2, 128, dec_b2, nullptr, dec, nullptr, 256, 256, 128, 0, 0, 0);
  mgemm(dec, wt + o_qkv, 256, mha_in_b, nullptr, nullptr, qkvb, 768, 768, 256, 0, 0, 1);
  hipLaunchKernelGGL(k_mha2s, dim3(NA/64, HH, NSLICE), dim3(256), 0, stream, qkvb, pacc, pm, pl);
  hipLaunchKernelGGL(k_mhacomb, dim3(NA), dim3(256), 0, stream, pacc, pm, pl, ctx);
  mgemm(ctx, wt + o_out, 256, mha_out_b, nullptr, agg, nullptr, 256, 256, 256, 0, 0, 0);
  mgemm(statesF, wt + o_gate, 512, nullptr, nullptr, g1, nullptr, 256, 256, 256, 0, 0, 0);
  mgemm(agg, wt + o_gate + 256, 512, gate_b1, nullptr, g1, nullptr, 256, 256, 256, 1, 1, 0);
  hipLaunchKernelGGL(k_gate, dim3(NA), dim3(256), 0, stream, g1, gate_W2, gate_b2, flag, agg, ag2);
  mgemm(ag2, wt + o_proj, 256, proj_b, statesF, nullptr, d_out, 256, 256, 256, 0, 0, 2);
}

// Round 13
// 396.569 us; speedup vs baseline: 1.1350x; 1.1350x over previous
//
#include <hip/hip_runtime.h>
#include <hip/hip_bf16.h>

#define NA 4096
#define DD 256
#define HH 4
#define CC 64
#define LL 2
#define TOPK 5
#define NSLICE 4

typedef __hip_bfloat16 bf16;
typedef __attribute__((ext_vector_type(8))) short bf16x8;
typedef __attribute__((ext_vector_type(4))) float f32x4;

__device__ __forceinline__ float b2f(bf16 v) { return __bfloat162float(v); }
__device__ __forceinline__ float u2f(unsigned int u) { union { unsigned int i; float f; } x; x.i = u; return x.f; }
__device__ __forceinline__ unsigned short f2bf(float f) {
  bf16 b = __float2bfloat16(f);
  return *reinterpret_cast<unsigned short*>(&b);
}
__device__ __forceinline__ float ldx(const void* p, size_t i, int bfm) {
  return bfm ? b2f(((const bf16*)p)[i]) : ((const float*)p)[i];
}
// strict ordering used by jax.lax.top_k: larger value first, ties -> smaller index
__device__ __forceinline__ bool kbetter(float v, int c, float v2, int c2) {
  return (v > v2) || (v == v2 && c < c2);
}
// monotone float->u32 key with col tie-break in low 12 bits (smaller col = larger key)
__device__ __forceinline__ unsigned int fkey(float f, int col) {
  unsigned int b = __float_as_uint(f);
  unsigned int u = ((int)b < 0) ? ~b : (b | 0x80000000u);
  return (u & 0xFFFFF000u) | (4095u - (unsigned int)col);
}

// ---------------- dtype detect: bf16 vs fp32 ----------------
__global__ __launch_bounds__(256) void k_detect(const void* probe, int* flag) {
  __shared__ int cnt;
  if (threadIdx.x == 0) cnt = 0;
  __syncthreads();
  const unsigned short* u = (const unsigned short*)probe;
  int bad = 0;
  for (int i = threadIdx.x; i < 2048; i += 256) {
    float v = u2f(((unsigned int)u[i]) << 16);
    if (!(fabsf(v) <= 1e10f)) bad++;
  }
  atomicAdd(&cnt, bad);
  __syncthreads();
  if (threadIdx.x == 0) flag[0] = (cnt < 64) ? 1 : 0;
}

// ---------------- weight transpose: Wt[n][k] = W[k][n], bf16 out, zero-pad n>=N ----------------
struct WtD { const void* src; long srcOff; int N; int K; long dstOff; };
struct WtArr { WtD d[10]; };

__global__ __launch_bounds__(256) void k_wT(WtArr wa, const int* __restrict__ flag, bf16* __restrict__ dst) {
  __shared__ unsigned short T[32][34];
  WtD de = wa.d[blockIdx.y];
  int bfm = flag[0];
  int Npad = ((de.N + 63) / 64) * 64;
  int tilesN = Npad >> 5, tilesK = de.K >> 5;
  int tile = blockIdx.x;
  if (tile >= tilesN * tilesK) return;
  int tn = tile % tilesN, tk = tile / tilesN;
  int t = threadIdx.x;
  {
    int kl = t >> 3, n4 = (t & 7) * 4;
    int kg = tk*32 + kl;
    #pragma unroll
    for (int j = 0; j < 4; j++) {
      int n = tn*32 + n4 + j;
      float v = (n < de.N) ? ldx(de.src, de.srcOff + (size_t)kg * de.N + n, bfm) : 0.0f;
      T[kl][n4 + j] = f2bf(v);
    }
  }
  __syncthreads();
  {
    int nl = t >> 3, k4 = (t & 7) * 4;
    size_t base = de.dstOff + (size_t)(tn*32 + nl) * de.K + tk*32 + k4;
    #pragma unroll
    for (int j = 0; j < 4; j++)
      ((unsigned short*)dst)[base + j] = T[k4 + j][nl];
  }
}

// ---------------- prep: statesF, enhanced, normalized rows (fp32 + bf16) ----------------
__global__ __launch_bounds__(256) void k_prep(
    const void* __restrict__ st, const void* __restrict__ em, const void* __restrict__ ro,
    const int* __restrict__ flag,
    float* __restrict__ statesF, float* __restrict__ enh, float* __restrict__ nsm,
    bf16* __restrict__ nsmh)
{
  int i = blockIdx.x, d = threadIdx.x;
  int bfm = flag[0];
  __shared__ float red[256];
  float s = ldx(st, (size_t)i*DD + d, bfm);
  statesF[i*DD + d] = s;
  float e = s + ldx(em, (size_t)i*DD + d, bfm) + ldx(ro, (size_t)i*64 + (d & 63), bfm);
  enh[i*DD + d] = e;
  red[d] = e * e;
  __syncthreads();
  for (int k = 128; k > 0; k >>= 1) { if (d < k) red[d] += red[d + k]; __syncthreads(); }
  float inv = 1.0f / fmaxf(sqrtf(red[0]), 1e-12f);
  float nv = e * inv;
  nsm[i*DD + d] = nv;
  nsmh[i*DD + d] = __float2bfloat16(nv);
}

// ---------------- MFMA sim + branchless top-8; LDS-staged B (coalesced), double-buffered ----------------
// grid (16 chunks, 64 row-blocks) x 256 threads (4 waves x 16 rows)
__global__ __launch_bounds__(256) void k_sim2(
    const bf16* __restrict__ nsmh, int* __restrict__ candI)
{
  __shared__ unsigned short Bs[2][16][264];   // 2 x 16 rows x 264 shorts = 16.9 KB
  int tid = threadIdx.x;
  int lane = tid & 63;
  int w = tid >> 6;
  int lr = lane & 15;
  int lg = lane >> 4;
  int chunk = blockIdx.x;
  int rb = blockIdx.y * 64;
  int cb = chunk * 256;
  const unsigned short* nsu = (const unsigned short*)nsmh;

  bf16x8 af[8];
  {
    const unsigned short* ap = nsu + (size_t)(rb + w*16 + lr)*DD + lg*8;
    #pragma unroll
    for (int kb = 0; kb < 8; kb++) af[kb] = *(const bf16x8*)(ap + kb*32);
  }

  unsigned int L0[8] = {0,0,0,0,0,0,0,0};
  unsigned int L1[8] = {0,0,0,0,0,0,0,0};
  unsigned int L2[8] = {0,0,0,0,0,0,0,0};
  unsigned int L3[8] = {0,0,0,0,0,0,0,0};

  int srow = tid >> 4;          // 0..15
  int sc16 = (tid & 15) * 16;   // 0..240, 32B per thread -> coalesced 512B/16 lanes
  {
    const unsigned short* src = nsu + (size_t)(cb + srow)*DD + sc16;
    *(bf16x8*)&Bs[0][srow][sc16]     = *(const bf16x8*)src;
    *(bf16x8*)&Bs[0][srow][sc16 + 8] = *(const bf16x8*)(src + 8);
  }

  #pragma unroll
  for (int ct = 0; ct < 16; ct++) {
    __syncthreads();   // staged buf[ct&1] visible; prior reads of buf[(ct+1)&1] done
    if (ct + 1 < 16) {
      const unsigned short* src = nsu + (size_t)(cb + (ct+1)*16 + srow)*DD + sc16;
      *(bf16x8*)&Bs[(ct+1)&1][srow][sc16]     = *(const bf16x8*)src;
      *(bf16x8*)&Bs[(ct+1)&1][srow][sc16 + 8] = *(const bf16x8*)(src + 8);
    }
    f32x4 z = (f32x4){0.f, 0.f, 0.f, 0.f};
    #pragma unroll
    for (int kb = 0; kb < 8; kb++) {
      bf16x8 bfr = *(bf16x8*)&Bs[ct & 1][lr][kb*32 + lg*8];
      z = __builtin_amdgcn_mfma_f32_16x16x32_bf16(af[kb], bfr, z, 0, 0, 0);
    }
    int c = cb + ct*16 + lr;
    unsigned int s0 = fkey(z[0], c), s1 = fkey(z[1], c), s2 = fkey(z[2], c), s3 = fkey(z[3], c);
    #pragma unroll
    for (int i = 0; i < 8; i++) {
      unsigned int h0 = max(L0[i], s0); s0 = min(L0[i], s0); L0[i] = h0;
      unsigned int h1 = max(L1[i], s1); s1 = min(L1[i], s1); L1[i] = h1;
      unsigned int h2 = max(L2[i], s2); s2 = min(L2[i], s2); L2[i] = h2;
      unsigned int h3 = max(L3[i], s3); s3 = min(L3[i], s3); L3[i] = h3;
    }
  }

  unsigned int* Ls[4] = { L0, L1, L2, L3 };
  #pragma unroll
  for (int r = 0; r < 4; r++) {
    unsigned int* a = Ls[r];
    #pragma unroll
    for (int st = 0; st < 4; st++) {
      const int msk = 1 << st;
      unsigned int t[8];
      #pragma unroll
      for (int i = 0; i < 8; i++) {
        unsigned int ob = __shfl_xor((int)a[7 - i], msk);
        t[i] = max(a[i], ob);
      }
      #pragma unroll
      for (int i = 0; i < 4; i++) {
        unsigned int hi = max(t[i], t[i+4]); unsigned int lo = min(t[i], t[i+4]);
        t[i] = hi; t[i+4] = lo;
      }
      #pragma unroll
      for (int g = 0; g < 8; g += 4) {
        #pragma unroll
        for (int i = 0; i < 2; i++) {
          unsigned int hi = max(t[g+i], t[g+i+2]); unsigned int lo = min(t[g+i], t[g+i+2]);
          t[g+i] = hi; t[g+i+2] = lo;
        }
      }
      #pragma unroll
      for (int g = 0; g < 8; g += 2) {
        unsigned int hi = max(t[g], t[g+1]); unsigned int lo = min(t[g], t[g+1]);
        t[g] = hi; t[g+1] = lo;
      }
      #pragma unroll
      for (int i = 0; i < 8; i++) a[i] = t[i];
    }
  }
  if (lr == 0) {
    #pragma unroll
    for (int r = 0; r < 4; r++) {
      int row = rb + w*16 + lg*4 + r;
      #pragma unroll
      for (int k = 0; k < 8; k++)
        candI[(size_t)row*128 + chunk*8 + k] = 4095 - (int)(Ls[r][k] & 0xFFFu);
    }
  }
}

// ---------------- exact fp32 rescore of 128 candidates -> top-5 + adjacency bits ----------------
// one block per row; 16 lane-groups x 8 candidates; wave-0 exact top-5 argmax
__global__ __launch_bounds__(256) void k_topk2(
    const float* __restrict__ nsb, const int* __restrict__ candI,
    unsigned long long* __restrict__ maskbits)
{
  __shared__ float sV[128];
  __shared__ int   sI[128];
  int row = blockIdx.x;
  int tid = threadIdx.x;
  int g = tid >> 4;        // group 0..15
  int l = tid & 15;        // lane-in-group
  const float* ap = &nsb[(size_t)row*DD];
  float4 a0 = *(const float4*)(ap + 0*64 + l*4);
  float4 a1 = *(const float4*)(ap + 1*64 + l*4);
  float4 a2 = *(const float4*)(ap + 2*64 + l*4);
  float4 a3 = *(const float4*)(ap + 3*64 + l*4);
  #pragma unroll
  for (int it = 0; it < 8; it++) {
    int c = g*8 + it;
    int ci = candI[(size_t)row*128 + c];
    const float* bp = &nsb[(size_t)ci*DD];
    float4 b0 = *(const float4*)(bp + 0*64 + l*4);
    float4 b1 = *(const float4*)(bp + 1*64 + l*4);
    float4 b2 = *(const float4*)(bp + 2*64 + l*4);
    float4 b3 = *(const float4*)(bp + 3*64 + l*4);
    float p = a0.x*b0.x + a0.y*b0.y + a0.z*b0.z + a0.w*b0.w
            + a1.x*b1.x + a1.y*b1.y + a1.z*b1.z + a1.w*b1.w
            + a2.x*b2.x + a2.y*b2.y + a2.z*b2.z + a2.w*b2.w
            + a3.x*b3.x + a3.y*b3.y + a3.z*b3.z + a3.w*b3.w;
    p += __shfl_xor(p, 1); p += __shfl_xor(p, 2);
    p += __shfl_xor(p, 4); p += __shfl_xor(p, 8);
    if (l == 0) { sV[c] = p; sI[c] = ci; }
  }
  __syncthreads();
  if (tid < 64) {
    float v0 = sV[tid], v1 = sV[64 + tid];
    int   i0 = sI[tid], i1 = sI[64 + tid];
    int sel[5];
    #pragma unroll
    for (int k = 0; k < 5; k++) {
      float bv; int bi;
      if (kbetter(v0, i0, v1, i1)) { bv = v0; bi = i0; } else { bv = v1; bi = i1; }
      #pragma unroll
      for (int off = 1; off < 64; off <<= 1) {
        float ov = __shfl_xor(bv, off); int oi = __shfl_xor(bi, off);
        if (kbetter(ov, oi, bv, bi)) { bv = ov; bi = oi; }
      }
      sel[k] = bi;
      if (i0 == bi) { v0 = -1e30f; i0 = 0x7fffffff; }
      if (i1 == bi) { v1 = -1e30f; i1 = 0x7fffffff; }
    }
    if (tid == 0) {
      atomicOr(&maskbits[(size_t)row*64 + (row >> 6)], 1ull << (row & 63));
      #pragma unroll
      for (int k = 0; k < 5; k++) {
        int j = sel[k];
        atomicOr(&maskbits[(size_t)row*64 + (j >> 6)], 1ull << (j & 63));
        atomicOr(&maskbits[(size_t)j*64 + (row >> 6)], 1ull << (row & 63));
      }
    }
  }
}

// ---------------- MFMA GEMM: C[M,N] = act(A[M,K] @ Wt^T + bias) (+resid / accF) ----------------
// R10 geometry: 64x64 tiles, grid (Npad/64, NA/64), 4 waves x 16-row strips
template<int KB>
__global__ __launch_bounds__(256) void k_mgemm(
    const float* __restrict__ A, const bf16* __restrict__ Bt, int ldB,
    const void* __restrict__ bias, const float* __restrict__ resid,
    const int* __restrict__ flag,
    float* __restrict__ Cf, void* __restrict__ Cb,
    int N, int act, int accF, int smode)
{
  int bfm = flag[0];
  int tid = threadIdx.x;
  int lane = tid & 63, w = tid >> 6;
  int lr = lane & 15, lg = lane >> 4;
  int n0 = blockIdx.x * 64, m0 = blockIdx.y * 64;
  const int K = KB * 32;
  int arow = m0 + w*16 + lr;

  bf16x8 af[KB];
  #pragma unroll
  for (int kb = 0; kb < KB; kb++) {
    const float* ap = A + (size_t)arow*K + kb*32 + lg*8;
    float4 v0 = *(const float4*)ap;
    float4 v1 = *(const float4*)(ap + 4);
    bf16x8 tt;
    tt[0] = (short)f2bf(v0.x); tt[1] = (short)f2bf(v0.y);
    tt[2] = (short)f2bf(v0.z); tt[3] = (short)f2bf(v0.w);
    tt[4] = (short)f2bf(v1.x); tt[5] = (short)f2bf(v1.y);
    tt[6] = (short)f2bf(v1.z); tt[7] = (short)f2bf(v1.w);
    af[kb] = tt;
  }

  f32x4 acc[4];
  #pragma unroll
  for (int ct = 0; ct < 4; ct++) acc[ct] = (f32x4){0.f,0.f,0.f,0.f};
  const unsigned short* bu = (const unsigned short*)Bt;
  #pragma unroll
  for (int ct = 0; ct < 4; ct++) {
    const unsigned short* bp = bu + (size_t)(n0 + ct*16 + lr)*ldB + lg*8;
    #pragma unroll
    for (int kb = 0; kb < KB; kb++) {
      bf16x8 bfr = *(const bf16x8*)(bp + kb*32);
      acc[ct] = __builtin_amdgcn_mfma_f32_16x16x32_bf16(af[kb], bfr, acc[ct], 0, 0, 0);
    }
  }

  #pragma unroll
  for (int ct = 0; ct < 4; ct++) {
    int col = n0 + ct*16 + lr;
    if (col >= N) continue;
    #pragma unroll
    for (int r = 0; r < 4; r++) {
      int orow = m0 + w*16 + lg*4 + r;
      size_t idx = (size_t)orow*N + col;
      float v = acc[ct][r];
      if (accF) v += Cf[idx];
      if (bias) v += ldx(bias, col, bfm);
      if (act == 1) v = fmaxf(v, 0.0f);
      if (resid) v += resid[idx];
      if (smode == 0) Cf[idx] = v;
      else if (smode == 1) ((bf16*)Cb)[idx] = __float2bfloat16(v);
      else {
        if (bfm) ((bf16*)Cb)[idx] = __float2bfloat16(v);
        else ((float*)Cb)[idx] = v;
      }
    }
  }
}

// ---------------- a_s, a_d ----------------
__global__ __launch_bounds__(256) void k_asd(
    const float* __restrict__ xs, const void* __restrict__ asrc, const void* __restrict__ adst,
    long loff, const int* __restrict__ flag,
    float* __restrict__ aS, float* __restrict__ aD)
{
  int i = blockIdx.x, t = threadIdx.x;
  int bfm = flag[0];
  __shared__ float rs[256], rd[256];
  float xv = xs[(size_t)i*DD + t];
  rs[t] = xv * ldx(asrc, loff + t, bfm);
  rd[t] = xv * ldx(adst, loff + t, bfm);
  __syncthreads();
  for (int k = 32; k > 0; k >>= 1) {
    if ((t & 63) < k) { rs[t] += rs[t + k]; rd[t] += rd[t + k]; }
    __syncthreads();
  }
  if ((t & 63) == 0) { int h = t >> 6; aS[i*HH + h] = rs[t]; aD[i*HH + h] = rd[t]; }
}

// ---------------- GAT aggregation + bias + LN + residual ----------------
__global__ __launch_bounds__(256) void k_gatagg(
    const float* __restrict__ xs, const float* __restrict__ aS, const float* __restrict__ aD,
    const unsigned long long* __restrict__ maskbits,
    const void* __restrict__ gbias, const void* __restrict__ lng, const void* __restrict__ lnb,
    long loff, const int* __restrict__ flag,
    const float* __restrict__ xold, float* __restrict__ xnew)
{
  __shared__ int nbr[NA];
  __shared__ float alph[NA];
  __shared__ float red[256];
  __shared__ float outv[DD];
  __shared__ int offs[64];
  __shared__ int degS;
  int j = blockIdx.x, t = threadIdx.x;
  int bfm = flag[0];
  unsigned long long bits = 0;
  if (t < 64) { bits = maskbits[(size_t)j*64 + t]; offs[t] = __popcll(bits); }
  __syncthreads();
  if (t == 0) { int run = 0; for (int w = 0; w < 64; w++) { int c = offs[w]; offs[w] = run; run += c; } degS = run; }
  __syncthreads();
  if (t < 64) {
    int base = offs[t];
    unsigned long long b = bits;
    while (b) { int p = __builtin_ctzll(b); nbr[base++] = t*64 + p; b &= b - 1; }
  }
  __syncthreads();
  int deg = degS;
  for (int h = 0; h < HH; h++) {
    float adjv = aD[j*HH + h];
    float lm = -1e30f;
    for (int n = t; n < deg; n += 256) {
      float lg = aS[nbr[n]*HH + h] + adjv;
      lg = (lg >= 0.f) ? lg : 0.2f*lg;
      alph[n] = lg;
      lm = fmaxf(lm, lg);
    }
    red[t] = lm; __syncthreads();
    for (int k = 128; k > 0; k >>= 1) { if (t < k) red[t] = fmaxf(red[t], red[t + k]); __syncthreads(); }
    float Mx = red[0];
    __syncthreads();
    float ls = 0.f;
    for (int n = t; n < deg; n += 256) { float w = __expf(alph[n] - Mx); alph[n] = w; ls += w; }
    red[t] = ls; __syncthreads();
    for (int k = 128; k > 0; k >>= 1) { if (t < k) red[t] += red[t + k]; __syncthreads(); }
    float Z = red[0];
    __syncthreads();
    int c = t & 63, q = t >> 6;
    float a2 = 0.f;
    for (int n = q; n < deg; n += 4) a2 += alph[n] * xs[(size_t)nbr[n]*DD + h*CC + c];
    red[t] = a2; __syncthreads();
    if (q == 0) outv[h*CC + c] = (red[c] + red[c+64] + red[c+128] + red[c+192]) / Z;
    __syncthreads();
  }
  float v = outv[t] + ldx(gbias, loff + t, bfm);
  red[t] = v; __syncthreads();
  for (int k = 128; k > 0; k >>= 1) { if (t < k) red[t] += red[t + k]; __syncthreads(); }
  float mu = red[0] * (1.0f/DD);
  __syncthreads();
  float dv = v - mu;
  red[t] = dv*dv; __syncthreads();
  for (int k = 128; k > 0; k >>= 1) { if (t < k) red[t] += red[t + k]; __syncthreads(); }
  float var = red[0] * (1.0f/DD);
  float xn = ldx(lng, loff + t, bfm) * dv * rsqrtf(var + 1e-5f) + ldx(lnb, loff + t, bfm) + xold[(size_t)j*DD + t];
  xnew[(size_t)j*DD + t] = xn;
}

// ---------------- KV-split MFMA flash-MHA with coalesced LDS staging ----------------
__global__ __launch_bounds__(256) void k_mha2s(
    const bf16* __restrict__ qkvb,
    bf16* __restrict__ pacc, float* __restrict__ pm, float* __restrict__ pl)
{
  __shared__ unsigned short Ks[64][72];
  __shared__ unsigned short Vts[64][72];
  __shared__ unsigned short Ps[4][16][72];
  int tid = threadIdx.x;
  int lane = tid & 63;
  int w = tid >> 6;
  int h = blockIdx.y;
  int q0 = blockIdx.x * 64;
  int sl = blockIdx.z;
  int lr = lane & 15;
  int lg = lane >> 4;

  const unsigned short* qkvu = (const unsigned short*)qkvb;

  bf16x8 qf0, qf1;
  {
    const unsigned short* qp = qkvu + (size_t)(q0 + w*16 + lr)*768 + h*64;
    qf0 = *(const bf16x8*)(qp + lg*8);
    qf1 = *(const bf16x8*)(qp + 32 + lg*8);
  }

  int sr = tid & 63;
  int sc = (tid >> 6) * 16;
  const unsigned short* kbase = qkvu + 256 + h*64;
  const unsigned short* vbase = qkvu + 512 + h*64;

  f32x4 oacc[4];
  #pragma unroll
  for (int c = 0; c < 4; c++) oacc[c] = (f32x4){0.f,0.f,0.f,0.f};
  float mrun[4], lrun[4];
  #pragma unroll
  for (int r = 0; r < 4; r++) { mrun[r] = -1e30f; lrun[r] = 0.f; }

  const int j0base = sl * (NA / NSLICE);
  bf16x8 kpa, kpb, vpa, vpb;
  {
    const unsigned short* kp = kbase + (size_t)(j0base + sr)*768 + sc;
    kpa = *(const bf16x8*)kp; kpb = *(const bf16x8*)(kp + 8);
    const unsigned short* vp = vbase + (size_t)(j0base + sr)*768 + sc;
    vpa = *(const bf16x8*)vp; vpb = *(const bf16x8*)(vp + 8);
  }

  for (int tile = 0; tile < (NA/NSLICE)/64; tile++) {
    int j0 = j0base + tile * 64;
    __syncthreads();
    *(bf16x8*)&Ks[sr][sc] = kpa;
    *(bf16x8*)&Ks[sr][sc+8] = kpb;
    {
      #pragma unroll
      for (int q = 0; q < 8; q++) Vts[sc + q][sr] = (unsigned short)vpa[q];
      #pragma unroll
      for (int q = 0; q < 8; q++) Vts[sc + 8 + q][sr] = (unsigned short)vpb[q];
    }
    __syncthreads();
    if (tile + 1 < (NA/NSLICE)/64) {
      const unsigned short* kp = kbase + (size_t)(j0 + 64 + sr)*768 + sc;
      kpa = *(const bf16x8*)kp; kpb = *(const bf16x8*)(kp + 8);
      const unsigned short* vp = vbase + (size_t)(j0 + 64 + sr)*768 + sc;
      vpa = *(const bf16x8*)vp; vpb = *(const bf16x8*)(vp + 8);
    }
    f32x4 sacc[4];
    #pragma unroll
    for (int ct = 0; ct < 4; ct++) {
      bf16x8 kf0 = *(bf16x8*)&Ks[ct*16 + lr][lg*8];
      bf16x8 kf1 = *(bf16x8*)&Ks[ct*16 + lr][32 + lg*8];
      f32x4 z = (f32x4){0.f,0.f,0.f,0.f};
      z = __builtin_amdgcn_mfma_f32_16x16x32_bf16(qf0, kf0, z, 0, 0, 0);
      z = __builtin_amdgcn_mfma_f32_16x16x32_bf16(qf1, kf1, z, 0, 0, 0);
      sacc[ct] = z;
    }
    #pragma unroll
    for (int r = 0; r < 4; r++) {
      float s0 = sacc[0][r]*0.125f, s1 = sacc[1][r]*0.125f;
      float s2 = sacc[2][r]*0.125f, s3 = sacc[3][r]*0.125f;
      float rm = fmaxf(fmaxf(s0, s1), fmaxf(s2, s3));
      rm = fmaxf(rm, __shfl_xor(rm, 1));
      rm = fmaxf(rm, __shfl_xor(rm, 2));
      rm = fmaxf(rm, __shfl_xor(rm, 4));
      rm = fmaxf(rm, __shfl_xor(rm, 8));
      float mn = fmaxf(mrun[r], rm);
      float corr = __expf(mrun[r] - mn);
      float p0 = __expf(s0 - mn), p1 = __expf(s1 - mn);
      float p2 = __expf(s2 - mn), p3 = __expf(s3 - mn);
      float ps = p0 + p1 + p2 + p3;
      ps += __shfl_xor(ps, 1); ps += __shfl_xor(ps, 2);
      ps += __shfl_xor(ps, 4); ps += __shfl_xor(ps, 8);
      mrun[r] = mn;
      lrun[r] = lrun[r]*corr + ps;
      #pragma unroll
      for (int c = 0; c < 4; c++) oacc[c][r] *= corr;
      int prow = lg*4 + r;
      Ps[w][prow][ 0 + lr] = f2bf(p0);
      Ps[w][prow][16 + lr] = f2bf(p1);
      Ps[w][prow][32 + lr] = f2bf(p2);
      Ps[w][prow][48 + lr] = f2bf(p3);
    }
    {
      bf16x8 pa0 = *(bf16x8*)&Ps[w][lr][lg*8];
      bf16x8 pa1 = *(bf16x8*)&Ps[w][lr][32 + lg*8];
      #pragma unroll
      for (int c = 0; c < 4; c++) {
        bf16x8 vf0 = *(bf16x8*)&Vts[c*16 + lr][lg*8];
        bf16x8 vf1 = *(bf16x8*)&Vts[c*16 + lr][32 + lg*8];
        oacc[c] = __builtin_amdgcn_mfma_f32_16x16x32_bf16(pa0, vf0, oacc[c], 0, 0, 0);
        oacc[c] = __builtin_amdgcn_mfma_f32_16x16x32_bf16(pa1, vf1, oacc[c], 0, 0, 0);
      }
    }
  }
  #pragma unroll
  for (int r = 0; r < 4; r++) {
    int row = q0 + w*16 + lg*4 + r;
    #pragma unroll
    for (int c = 0; c < 4; c++)
      pacc[((size_t)sl*NA + row)*DD + h*CC + c*16 + lr] = __float2bfloat16(oacc[c][r]);
  }
  if (lr == 0) {
    #pragma unroll
    for (int r = 0; r < 4; r++) {
      int row = q0 + w*16 + lg*4 + r;
      pm[((size_t)sl*HH + h)*NA + row] = mrun[r];
      pl[((size_t)sl*HH + h)*NA + row] = lrun[r];
    }
  }
}

// ---------------- combine KV-split partials ----------------
__global__ __launch_bounds__(256) void k_mhacomb(
    const bf16* __restrict__ pacc, const float* __restrict__ pm, const float* __restrict__ pl,
    float* __restrict__ ctx)
{
  int row = blockIdx.x, col = threadIdx.x;
  int h = col >> 6;
  float ms[NSLICE];
  float M = -1e30f;
  #pragma unroll
  for (int s = 0; s < NSLICE; s++) { ms[s] = pm[((size_t)s*HH + h)*NA + row]; M = fmaxf(M, ms[s]); }
  float O = 0.f, L = 0.f;
  #pragma unroll
  for (int s = 0; s < NSLICE; s++) {
    float e = __expf(ms[s] - M);
    O += e * b2f(pacc[((size_t)s*NA + row)*DD + col]);
    L += e * pl[((size_t)s*HH + h)*NA + row];
  }
  ctx[(size_t)row*DD + col] = O / L;
}

// ---------------- gate ----------------
__global__ __launch_bounds__(256) void k_gate(
    const float* __restrict__ g1, const void* __restrict__ w2, const void* __restrict__ b2v,
    const int* __restrict__ flag,
    const float* __restrict__ agg, float* __restrict__ ag2)
{
  int i = blockIdx.x, t = threadIdx.x;
  int bfm = flag[0];
  __shared__ float red[256];
  red[t] = g1[(size_t)i*DD + t] * ldx(w2, t, bfm);
  __syncthreads();
  for (int k = 128; k > 0; k >>= 1) { if (t < k) red[t] += red[t + k]; __syncthreads(); }
  float sr = red[0] + ldx(b2v, 0, bfm);
  float s = 1.0f / (1.0f + __expf(-sr));
  ag2[(size_t)i*DD + t] = agg[(size_t)i*DD + t] * s;
}

extern "C" void kernel_launch(void* const* d_in, const int* in_sizes, int n_in,
                              void* d_out, int out_size, void* d_ws, size_t ws_size,
                              hipStream_t stream) {
  (void)in_sizes; (void)n_in; (void)out_size; (void)ws_size;
  const void* agent_states = d_in[0];
  const void* agent_emb    = d_in[1];
  const void* role_emb     = d_in[2];
  const void* gat_W        = d_in[3];
  const void* gat_att_src  = d_in[4];
  const void* gat_att_dst  = d_in[5];
  const void* gat_bias     = d_in[6];
  const void* ln_gamma     = d_in[7];
  const void* ln_beta      = d_in[8];
  const void* enc_W1 = d_in[9];
  const void* enc_b1 = d_in[10];
  const void* enc_W2 = d_in[11];
  const void* enc_b2 = d_in[12];
  const void* dec_W1 = d_in[13];
  const void* dec_b1 = d_in[14];
  const void* dec_W2 = d_in[15];
  const void* dec_b2 = d_in[16];
  const void* mha_in_w  = d_in[17];
  const void* mha_in_b  = d_in[18];
  const void* mha_out_w = d_in[19];
  const void* mha_out_b = d_in[20];
  const void* proj_W = d_in[21];
  const void* proj_b = d_in[22];
  const void* gate_W1 = d_in[23];
  const void* gate_b1 = d_in[24];
  const void* gate_W2 = d_in[25];
  const void* gate_b2 = d_in[26];

  char* base = (char*)d_ws;
  size_t off = 0;
  auto alloc = [&](size_t nbytes) -> char* {
    char* p = base + off; off += (nbytes + 255) & ~(size_t)255; return p;
  };
  int* flag = (int*)alloc(256);
  float* statesF = (float*)alloc((size_t)NA*DD*4);
  float* enh     = (float*)alloc((size_t)NA*DD*4);
  float* nsb     = (float*)alloc((size_t)NA*DD*4);
  bf16*  nsbh    = (bf16*)alloc((size_t)NA*DD*2);
  unsigned long long* maskbits = (unsigned long long*)alloc((size_t)NA*64*8);
  float* xs  = (float*)alloc((size_t)NA*DD*4);
  float* xB  = (float*)alloc((size_t)NA*DD*4);
  bf16*  qkvb = (bf16*)alloc((size_t)NA*3*DD*2);
  float* dec = (float*)alloc((size_t)NA*DD*4);
  float* agg = (float*)alloc((size_t)NA*DD*4);
  int*   candI = (int*)alloc((size_t)NA*128*4);
  bf16*  wt    = (bf16*)alloc((size_t)647168*2);
  bf16*  pacc  = (bf16*)alloc((size_t)NSLICE*NA*DD*2);
  float* pm    = (float*)alloc((size_t)NSLICE*HH*NA*4);
  float* pl    = (float*)alloc((size_t)NSLICE*HH*NA*4);
  float* xC  = enh;
  float* aS  = nsb;               // nsb free after k_topk2
  float* aD  = nsb + NA*HH;
  float* h1  = nsb + 2*NA*HH;
  float* msg = h1 + (size_t)NA*64;
  float* dh  = msg + (size_t)NA*32;
  float* ctx = dec;
  float* g1  = xs;
  float* ag2 = xB;

  // transposed-weight element offsets (each block is [Npad][K] bf16)
  const long o_gat0 = 0,      o_gat1 = 65536,  o_enc1 = 131072, o_enc2 = 147456;
  const long o_dec1 = 151552, o_dec2 = 155648, o_qkv  = 188416, o_out  = 385024;
  const long o_gate = 450560, o_proj = 581632;

  WtArr wa;
  wa.d[0] = { gat_W,     0,      256, 256, o_gat0 };
  wa.d[1] = { gat_W,     65536,  256, 256, o_gat1 };
  wa.d[2] = { enc_W1,    0,       64, 256, o_enc1 };
  wa.d[3] = { enc_W2,    0,       32,  64, o_enc2 };
  wa.d[4] = { dec_W1,    0,      128,  32, o_dec1 };
  wa.d[5] = { dec_W2,    0,      256, 128, o_dec2 };
  wa.d[6] = { mha_in_w,  0,      768, 256, o_qkv  };
  wa.d[7] = { mha_out_w, 0,      256, 256, o_out  };
  wa.d[8] = { gate_W1,   0,      256, 512, o_gate };
  wa.d[9] = { proj_W,    0,      256, 256, o_proj };

  auto mgemm = [&](const float* A, const bf16* Bt, int ldB, const void* bias,
                   const float* resid, float* Cf, void* Cb,
                   int N, int Npad, int K, int act, int accF, int smode) {
    dim3 g(Npad/64, NA/64);
    switch (K/32) {
      case 1: hipLaunchKernelGGL(k_mgemm<1>, g, dim3(256), 0, stream, A, Bt, ldB, bias, resid, flag, Cf, Cb, N, act, accF, smode); break;
      case 2: hipLaunchKernelGGL(k_mgemm<2>, g, dim3(256), 0, stream, A, Bt, ldB, bias, resid, flag, Cf, Cb, N, act, accF, smode); break;
      case 4: hipLaunchKernelGGL(k_mgemm<4>, g, dim3(256), 0, stream, A, Bt, ldB, bias, resid, flag, Cf, Cb, N, act, accF, smode); break;
      default: hipLaunchKernelGGL(k_mgemm<8>, g, dim3(256), 0, stream, A, Bt, ldB, bias, resid, flag, Cf, Cb, N, act, accF, smode); break;
    }
  };

  hipMemsetAsync(maskbits, 0, (size_t)NA*64*8, stream);
  hipLaunchKernelGGL(k_detect, dim3(1), dim3(256), 0, stream, agent_states, flag);
  hipLaunchKernelGGL(k_wT, dim3(192, 10), dim3(256), 0, stream, wa, flag, wt);
  hipLaunchKernelGGL(k_prep, dim3(NA), dim3(256), 0, stream,
                     agent_states, agent_emb, role_emb, flag, statesF, enh, nsb, nsbh);
  hipLaunchKernelGGL(k_sim2, dim3(16, NA/64), dim3(256), 0, stream, nsbh, candI);
  hipLaunchKernelGGL(k_topk2, dim3(NA), dim3(256), 0, stream, nsb, candI, maskbits);

  const float* xin = enh;
  float* xout = xB;
  for (int l = 0; l < LL; l++) {
    mgemm(xin, wt + (l ? o_gat1 : o_gat0), 256, nullptr, nullptr, xs, nullptr, 256, 256, 256, 0, 0, 0);
    hipLaunchKernelGGL(k_asd, dim3(NA), dim3(256), 0, stream,
                       xs, gat_att_src, gat_att_dst, (long)l*DD, flag, aS, aD);
    hipLaunchKernelGGL(k_gatagg, dim3(NA), dim3(256), 0, stream,
                       xs, aS, aD, maskbits, gat_bias, ln_gamma, ln_beta, (long)l*DD, flag, xin, xout);
    xin = xout; xout = xC;
  }
  mgemm(xin, wt + o_enc1, 256, enc_b1, nullptr, h1, nullptr, 64, 64, 256, 1, 0, 0);
  mgemm(h1, wt + o_enc2, 64, enc_b2, nullptr, msg, nullptr, 32, 64, 64, 0, 0, 0);
  mgemm(msg, wt + o_dec1, 32, dec_b1, nullptr, dh, nullptr, 128, 128, 32, 1, 0, 0);
  mgemm(dh, wt + o_dec2, 128, dec_b2, nullptr, dec, nullptr, 256, 256, 128, 0, 0, 0);
  mgemm(dec, wt + o_qkv, 256, mha_in_b, nullptr, nullptr, qkvb, 768, 768, 256, 0, 0, 1);
  hipLaunchKernelGGL(k_mha2s, dim3(NA/64, HH, NSLICE), dim3(256), 0, stream, qkvb, pacc, pm, pl);
  hipLaunchKernelGGL(k_mhacomb, dim3(NA), dim3(256), 0, stream, pacc, pm, pl, ctx);
  mgemm(ctx, wt + o_out, 256, mha_out_b, nullptr, agg, nullptr, 256, 256, 256, 0, 0, 0);
  mgemm(statesF, wt + o_gate, 512, nullptr, nullptr, g1, nullptr, 256, 256, 256, 0, 0, 0);
  mgemm(agg, wt + o_gate + 256, 512, gate_b1, nullptr, g1, nullptr, 256, 256, 256, 1, 1, 0);
  hipLaunchKernelGGL(k_gate, dim3(NA), dim3(256), 0, stream, g1, gate_W2, gate_b2, flag, agg, ag2);
  mgemm(ag2, wt + o_proj, 256, proj_b, statesF, nullptr, d_out, 256, 256, 256, 0, 0, 2);
}